// Round 4
// baseline (415.958 us; speedup 1.0000x reference)
//
#include <hip/hip_runtime.h>
#include <hip/hip_bf16.h>

namespace {
constexpr int kB = 16, kT = 2048, kC = 512, kH = 4, kU = 250, kDH = 128;
constexpr int kUT = 64;   // u-tile per block in k3
constexpr int kNUT = 4;   // ceil(250/64)
constexpr int kTT = 64;   // t-tile in k3
}

// ---------------- K1: alpha prediction branch ----------------
// one wave per (b,t); lane handles 8 channels; wave-reduce the lin_w dot.
__global__ __launch_bounds__(256) void k1_alpha(
    const float* __restrict__ hid, const float* __restrict__ mask,
    const float* __restrict__ conv_w, const float* __restrict__ conv_b,
    const float* __restrict__ lin_w, const float* __restrict__ lin_b,
    float* __restrict__ alpha_raw)
{
    const int wave = threadIdx.x >> 6;
    const int lane = threadIdx.x & 63;
    const int i = blockIdx.x * 4 + wave;          // flat (b,t)
    const int t = i & (kT - 1);
    const int c0 = lane * 8;
    const float* row = hid + (size_t)i * kC + c0;

    float h0[8], hm[8], hp[8];
    {
        float4 a = *(const float4*)row;
        float4 b4 = *(const float4*)(row + 4);
        h0[0]=a.x; h0[1]=a.y; h0[2]=a.z; h0[3]=a.w;
        h0[4]=b4.x; h0[5]=b4.y; h0[6]=b4.z; h0[7]=b4.w;
    }
    if (t > 0) {
        float4 a = *(const float4*)(row - kC);
        float4 b4 = *(const float4*)(row - kC + 4);
        hm[0]=a.x; hm[1]=a.y; hm[2]=a.z; hm[3]=a.w;
        hm[4]=b4.x; hm[5]=b4.y; hm[6]=b4.z; hm[7]=b4.w;
    } else {
        #pragma unroll
        for (int j = 0; j < 8; j++) hm[j] = 0.f;
    }
    if (t < kT - 1) {
        float4 a = *(const float4*)(row + kC);
        float4 b4 = *(const float4*)(row + kC + 4);
        hp[0]=a.x; hp[1]=a.y; hp[2]=a.z; hp[3]=a.w;
        hp[4]=b4.x; hp[5]=b4.y; hp[6]=b4.z; hp[7]=b4.w;
    } else {
        #pragma unroll
        for (int j = 0; j < 8; j++) hp[j] = 0.f;
    }

    float acc = 0.f;
    #pragma unroll
    for (int j = 0; j < 8; j++) {
        int c = c0 + j;
        float w0 = conv_w[c * 3 + 0];
        float w1 = conv_w[c * 3 + 1];
        float w2 = conv_w[c * 3 + 2];
        float m = fmaf(hm[j], w0, fmaf(h0[j], w1, fmaf(hp[j], w2, conv_b[c])));
        float v = m + h0[j];                       // memory + context
        v = v > 0.f ? v : 0.f;                     // relu
        acc = fmaf(v, lin_w[c], acc);
    }
    #pragma unroll
    for (int off = 32; off >= 1; off >>= 1) acc += __shfl_xor(acc, off, 64);

    if (lane == 0) {
        float s = acc + lin_b[0];
        float a = 1.f / (1.f + expf(-s));          // relu(sigmoid*1-0) == sigmoid
        a *= mask[i];
        alpha_raw[i] = a;
    }
}

// ---------------- K2: token_num, scaling, cumsum (alignment) ----------------
__global__ __launch_bounds__(256) void k2_scan(
    const float* __restrict__ alpha_raw, const int* __restrict__ target,
    float* __restrict__ align_out,
    float* __restrict__ out_tok, float* __restrict__ out_alpha)
{
    __shared__ float sums[256];
    __shared__ float offs[256];
    __shared__ float s_scale;
    const int b = blockIdx.x;
    const int tid = threadIdx.x;
    const float* ar = alpha_raw + (size_t)b * kT + tid * 8;
    float raw[8], pre[8];
    float s = 0.f;
    #pragma unroll
    for (int j = 0; j < 8; j++) { raw[j] = ar[j]; s += raw[j]; pre[j] = s; }
    sums[tid] = s;
    __syncthreads();
    if (tid == 0) {
        float run = 0.f;
        for (int i = 0; i < 256; i++) { offs[i] = run; run += sums[i]; }
        float tgtf = (float)target[b];
        s_scale = (run != 0.f) ? (tgtf / run) : 0.f;
        out_tok[b] = run;                          // pre-scale sum (f32 out)
    }
    __syncthreads();
    const float scale = s_scale;
    const float base = offs[tid];
    float* al = align_out + (size_t)b * kT + tid * 8;
    float* oa = out_alpha + (size_t)b * kT + tid * 8;
    #pragma unroll
    for (int j = 0; j < 8; j++) {
        al[j] = (base + pre[j]) * scale;           // cumsum of scaled alphas
        oa[j] = raw[j] * scale;                    // scaled alphas (f32 out)
    }
}

// ---------------- K3: Gaussian soft-segment attention ----------------
// block = (u-tile=64, one (b,h)); two-pass softmax over t; stream 64-t tiles.
// sigma_bias cancels in the softmax (constant over t) -> omitted.
__global__ __launch_bounds__(256) void k3_attn(
    const float* __restrict__ hid, const float* __restrict__ mask,
    const float* __restrict__ align, const float* __restrict__ sigma,
    float* __restrict__ out_ac)
{
    __shared__ float al_s[kT];                 // 8 KB
    __shared__ unsigned int mb_s[kT / 32];     // mask bits, 256 B
    __shared__ float m_s[kUT], linv_s[kUT];
    __shared__ float red_m[kUT * 4], red_l[kUT * 4];
    __shared__ float hn_s[kTT][132];           // +4 pad, 33 KB
    __shared__ float w_s[kTT][kUT];            // [t][u], 16 KB

    const int ut = blockIdx.x, h = blockIdx.y, b = blockIdx.z;
    const int tid = threadIdx.x;
    const int u0 = ut * kUT;
    const float sig = sigma[h];

    for (int t = tid; t < kT; t += 256) al_s[t] = align[(size_t)b * kT + t];
    if (tid < kT / 32) {
        unsigned int bits = 0;
        const float* mp = mask + b * kT + tid * 32;
        #pragma unroll
        for (int j = 0; j < 32; j++) if (mp[j] > 0.f) bits |= (1u << j);
        mb_s[tid] = bits;
    }
    __syncthreads();

    // pass 1: online softmax stats; lane = u, wave = t-phase (broadcast al_s reads)
    {
        const int u_l = tid & 63;
        const int q = tid >> 6;
        const float du = (float)(u0 + u_l) + 0.5f;
        float m = -1.0e30f, l = 0.f;
        for (int t = q; t < kT; t += 4) {
            if ((mb_s[t >> 5] >> (t & 31)) & 1) {
                float d = (du - al_s[t]) * sig;
                float sc = -(d * d);
                if (sc > m) { l = l * __expf(m - sc) + 1.f; m = sc; }
                else l += __expf(sc - m);
            }
        }
        red_m[u_l * 4 + q] = m; red_l[u_l * 4 + q] = l;
    }
    __syncthreads();
    if (tid < kUT) {
        float M = red_m[tid * 4];
        #pragma unroll
        for (int q = 1; q < 4; q++) M = fmaxf(M, red_m[tid * 4 + q]);
        float L = 0.f;
        #pragma unroll
        for (int q = 0; q < 4; q++)
            L += red_l[tid * 4 + q] * __expf(fminf(red_m[tid * 4 + q] - M, 0.f));
        m_s[tid] = M;
        linv_s[tid] = (L > 0.f) ? 1.f / L : 0.f;
    }
    __syncthreads();

    // pass 2: stream t-tiles; acc tile 8u x 4d per thread
    const int ugrp = tid >> 5;        // 0..7  -> u = ugrp*8 .. +8
    const int dgrp = tid & 31;        // d = dgrp*4 .. +4
    float acc[8][4];
    #pragma unroll
    for (int iu = 0; iu < 8; iu++)
        #pragma unroll
        for (int id = 0; id < 4; id++) acc[iu][id] = 0.f;

    const float* hb = hid + (size_t)b * kT * kC + h * kDH;

    for (int t0 = 0; t0 < kT; t0 += kTT) {
        // issue global loads first (hide latency behind exp work)
        float4 ld[8];
        {
            const int r = tid >> 2;
            const int cbase = (tid & 3) * 32;
            const float* src = hb + (size_t)(t0 + r) * kC + cbase;
            #pragma unroll
            for (int q = 0; q < 8; q++) ld[q] = *(const float4*)(src + q * 4);
        }
        // weight tile: lane = u (conflict-free w_s writes), 16 t rows per thread
        {
            const int u_l = tid & 63;
            const int wv = tid >> 6;
            const float du = (float)(u0 + u_l) + 0.5f;
            const float mm = m_s[u_l];
            const float li = linv_s[u_l];
            #pragma unroll
            for (int j = 0; j < 16; j++) {
                int tl = wv * 16 + j;
                int t = t0 + tl;
                float d = (du - al_s[t]) * sig;
                float e = ((mb_s[t >> 5] >> (t & 31)) & 1)
                            ? __expf(fminf(-(d * d) - mm, 0.f)) * li : 0.f;
                w_s[tl][u_l] = e;
            }
        }
        // store hn tile
        {
            const int r = tid >> 2;
            const int cbase = (tid & 3) * 32;
            #pragma unroll
            for (int q = 0; q < 8; q++)
                *(float4*)&hn_s[r][cbase + q * 4] = ld[q];
        }
        __syncthreads();

        #pragma unroll 2
        for (int tl = 0; tl < kTT; tl++) {
            float hv[4], wv8[8];
            *(float4*)&hv[0]  = *(const float4*)&hn_s[tl][dgrp * 4];
            *(float4*)&wv8[0] = *(const float4*)&w_s[tl][ugrp * 8];
            *(float4*)&wv8[4] = *(const float4*)&w_s[tl][ugrp * 8 + 4];
            #pragma unroll
            for (int iu = 0; iu < 8; iu++)
                #pragma unroll
                for (int id = 0; id < 4; id++)
                    acc[iu][id] = fmaf(wv8[iu], hv[id], acc[iu][id]);
        }
        __syncthreads();
    }

    // epilogue: out[b, u, h*128 + d]  (f32 out)
    #pragma unroll
    for (int iu = 0; iu < 8; iu++) {
        int u = u0 + ugrp * 8 + iu;
        if (u < kU) {
            float* dst = out_ac + ((size_t)(b * kU + u)) * kC + h * kDH + dgrp * 4;
            #pragma unroll
            for (int id = 0; id < 4; id++) dst[id] = acc[iu][id];
        }
    }
}

extern "C" void kernel_launch(void* const* d_in, const int* in_sizes, int n_in,
                              void* d_out, int out_size, void* d_ws, size_t ws_size,
                              hipStream_t stream) {
    const float* hid    = (const float*)d_in[0];
    const float* mask   = (const float*)d_in[1];
    const int*   tgt    = (const int*)d_in[2];
    // d_in[3] = max_token scalar (compile-time kU=250)
    const float* conv_w = (const float*)d_in[4];
    const float* conv_b = (const float*)d_in[5];
    const float* lin_w  = (const float*)d_in[6];
    const float* lin_b  = (const float*)d_in[7];
    const float* sigma  = (const float*)d_in[8];
    // d_in[9] = sigma_bias: constant over t -> cancels in softmax; unused.

    float* alpha_raw = (float*)d_ws;
    float* align     = alpha_raw + (size_t)kB * kT;

    float* out_ac    = (float*)d_out;                    // [B, U, C]
    float* out_tok   = out_ac + (size_t)kB * kU * kC;    // [B]
    float* out_alpha = out_tok + kB;                     // [B, T]

    k1_alpha<<<kB * kT / 4, 256, 0, stream>>>(hid, mask, conv_w, conv_b, lin_w, lin_b, alpha_raw);
    k2_scan<<<kB, 256, 0, stream>>>(alpha_raw, tgt, align, out_tok, out_alpha);
    k3_attn<<<dim3(kNUT, kH, kB), 256, 0, stream>>>(hid, mask, align, sigma, out_ac);
}

// Round 5
// 206.143 us; speedup vs baseline: 2.0178x; 2.0178x over previous
//
#include <hip/hip_runtime.h>
#include <hip/hip_bf16.h>

namespace {
constexpr int kB = 16, kT = 2048, kC = 512, kH = 4, kU = 250, kDH = 128;
constexpr int kTC = 8;                 // t-chunks for k3
constexpr int kTChunk = kT / kTC;      // 256
}

typedef __attribute__((ext_vector_type(8))) short short8;
typedef __attribute__((ext_vector_type(4))) float float4v;

__device__ __forceinline__ short f2bf(float x) {
    union { float f; unsigned int u; } v; v.f = x;
    unsigned int r = (v.u + 0x7FFFu + ((v.u >> 16) & 1u)) >> 16;
    return (short)r;
}

// ---------------- K1: alpha prediction branch ----------------
// one wave per (b,t); lane handles 8 channels; weights staged in LDS.
__global__ __launch_bounds__(256) void k1_alpha(
    const float* __restrict__ hid, const float* __restrict__ mask,
    const float* __restrict__ conv_w, const float* __restrict__ conv_b,
    const float* __restrict__ lin_w, const float* __restrict__ lin_b,
    float* __restrict__ alpha_raw)
{
    __shared__ float wl[1536 + 512 + 512];   // conv_w | conv_b | lin_w
    const int tid = threadIdx.x;
    for (int i = tid; i < 384; i += 256) ((float4*)&wl[0])[i]    = ((const float4*)conv_w)[i];
    for (int i = tid; i < 128; i += 256) ((float4*)&wl[1536])[i] = ((const float4*)conv_b)[i];
    for (int i = tid; i < 128; i += 256) ((float4*)&wl[2048])[i] = ((const float4*)lin_w)[i];
    __syncthreads();

    const int wave = tid >> 6;
    const int lane = tid & 63;
    const int i = blockIdx.x * 4 + wave;          // flat (b,t)
    const int t = i & (kT - 1);
    const int c0 = lane * 8;
    const float* row = hid + (size_t)i * kC + c0;

    float h0[8], hm[8], hp[8];
    {
        float4 a = *(const float4*)row;
        float4 b4 = *(const float4*)(row + 4);
        h0[0]=a.x; h0[1]=a.y; h0[2]=a.z; h0[3]=a.w;
        h0[4]=b4.x; h0[5]=b4.y; h0[6]=b4.z; h0[7]=b4.w;
    }
    if (t > 0) {
        float4 a = *(const float4*)(row - kC);
        float4 b4 = *(const float4*)(row - kC + 4);
        hm[0]=a.x; hm[1]=a.y; hm[2]=a.z; hm[3]=a.w;
        hm[4]=b4.x; hm[5]=b4.y; hm[6]=b4.z; hm[7]=b4.w;
    } else {
        #pragma unroll
        for (int j = 0; j < 8; j++) hm[j] = 0.f;
    }
    if (t < kT - 1) {
        float4 a = *(const float4*)(row + kC);
        float4 b4 = *(const float4*)(row + kC + 4);
        hp[0]=a.x; hp[1]=a.y; hp[2]=a.z; hp[3]=a.w;
        hp[4]=b4.x; hp[5]=b4.y; hp[6]=b4.z; hp[7]=b4.w;
    } else {
        #pragma unroll
        for (int j = 0; j < 8; j++) hp[j] = 0.f;
    }

    const float* cw = &wl[c0 * 3];
    const float* cb = &wl[1536 + c0];
    const float* lw = &wl[2048 + c0];
    float acc = 0.f;
    #pragma unroll
    for (int j = 0; j < 8; j++) {
        float m = fmaf(hm[j], cw[j*3+0], fmaf(h0[j], cw[j*3+1], fmaf(hp[j], cw[j*3+2], cb[j])));
        float v = m + h0[j];                       // memory + context
        v = v > 0.f ? v : 0.f;                     // relu
        acc = fmaf(v, lw[j], acc);
    }
    #pragma unroll
    for (int off = 32; off >= 1; off >>= 1) acc += __shfl_xor(acc, off, 64);

    if (lane == 0) {
        float s = acc + lin_b[0];
        float a = 1.f / (1.f + expf(-s));          // relu(sigmoid*1-0) == sigmoid
        a *= mask[i];
        alpha_raw[i] = a;
    }
}

// ---------------- K2: token_num, scaling, cumsum (+mask-folded alignment) --------
__global__ __launch_bounds__(256) void k2_scan(
    const float* __restrict__ alpha_raw, const float* __restrict__ mask,
    const int* __restrict__ target,
    float* __restrict__ align_out,
    float* __restrict__ out_tok, float* __restrict__ out_alpha)
{
    __shared__ float sums[256];
    __shared__ float offs[256];
    __shared__ float s_scale;
    const int b = blockIdx.x;
    const int tid = threadIdx.x;
    const float* ar = alpha_raw + (size_t)b * kT + tid * 8;
    float raw[8], pre[8];
    float s = 0.f;
    #pragma unroll
    for (int j = 0; j < 8; j++) { raw[j] = ar[j]; s += raw[j]; pre[j] = s; }
    sums[tid] = s;
    __syncthreads();
    if (tid == 0) {
        float run = 0.f;
        for (int i = 0; i < 256; i++) { offs[i] = run; run += sums[i]; }
        float tgtf = (float)target[b];
        s_scale = (run != 0.f) ? (tgtf / run) : 0.f;
        out_tok[b] = run;                          // pre-scale sum
    }
    __syncthreads();
    const float scale = s_scale;
    const float base = offs[tid];
    const float* mp = mask + (size_t)b * kT + tid * 8;
    float* al = align_out + (size_t)b * kT + tid * 8;
    float* oa = out_alpha + (size_t)b * kT + tid * 8;
    #pragma unroll
    for (int j = 0; j < 8; j++) {
        float cum = (base + pre[j]) * scale;       // cumsum of scaled alphas
        // fold mask into alignment: masked t -> huge value -> weight exp(-inf)=0
        al[j] = (mp[j] > 0.f) ? cum : 1.0e30f;
        oa[j] = raw[j] * scale;                    // scaled alphas
    }
}

// ---------------- K3: MFMA Gaussian soft-segment attention ----------------
// grid (tc=8, h=4, b=16); block 256 thr = 4 waves, wave owns 64 u (4 M-tiles).
// P generated analytically in A-frag layout (A[m=lane&15][k=quad*8+j], m120-verified).
// V staged f32->bf16 transposed in LDS; B-frag = single ds_read_b128.
// Unnormalized O + per-u l accumulated via atomicAdd; k4 normalizes.
__global__ __launch_bounds__(256) void k3_attn(
    const float* __restrict__ hid, const float* __restrict__ align_m,
    const float* __restrict__ sigma,
    float* __restrict__ out_ac, float* __restrict__ l_ws)
{
    __shared__ float al_s[kTChunk];              // 1 KB
    __shared__ unsigned short bT[128][72];       // [d][t] bf16, pad 72 (18.4 KB)

    const int tc = blockIdx.x, h = blockIdx.y, b = blockIdx.z;
    const int tid = threadIdx.x;
    const int wave = tid >> 6, lane = tid & 63;
    const int lm = lane & 15, quad = lane >> 4;
    const int t0 = tc * kTChunk;
    const float sig = sigma[h];

    if (tid < kTChunk) al_s[tid] = align_m[(size_t)b * kT + t0 + tid];

    const int u_base = wave * 64;
    float dus[4];
    #pragma unroll
    for (int mt = 0; mt < 4; mt++)
        dus[mt] = ((float)(u_base + mt * 16 + lm) + 0.5f) * sig;

    float4v acc[4][8];
    #pragma unroll
    for (int mt = 0; mt < 4; mt++)
        #pragma unroll
        for (int nt = 0; nt < 8; nt++)
            acc[mt][nt] = (float4v)(0.f);
    float lsum[4] = {0.f, 0.f, 0.f, 0.f};

    // staging thread->elements mapping (constant across super-tiles)
    const int dq  = ((tid & 3) + 4 * (tid >> 5)) * 4;   // d0 in 0..124 step 4
    const int tpb = (tid >> 2) & 7;                     // t-pair base

    for (int st = 0; st < kTChunk; st += 64) {
        __syncthreads();   // protect bT from previous-iteration readers
        // stage 64t x 128d, f32 -> bf16, transposed [d][t]
        #pragma unroll
        for (int q = 0; q < 4; q++) {
            int tl = (tpb + 8 * q) * 2;
            const float* src = hid + ((size_t)b * kT + t0 + st + tl) * kC + h * kDH + dq;
            float4 r0 = *(const float4*)src;
            float4 r1 = *(const float4*)(src + kC);
            const float* p0 = (const float*)&r0;
            const float* p1 = (const float*)&r1;
            #pragma unroll
            for (int i2 = 0; i2 < 4; i2++) {
                unsigned int lo = (unsigned int)(unsigned short)f2bf(p0[i2]);
                unsigned int hi = (unsigned int)(unsigned short)f2bf(p1[i2]);
                *(unsigned int*)&bT[dq + i2][tl] = lo | (hi << 16);
            }
        }
        __syncthreads();

        #pragma unroll
        for (int ks = 0; ks < 2; ks++) {
            // align values for this wave-lane's 8 k-positions
            float alv[8];
            const int abase = st + ks * 32 + quad * 8;
            *(float4*)&alv[0] = *(const float4*)&al_s[abase];
            *(float4*)&alv[4] = *(const float4*)&al_s[abase + 4];

            short8 afrag[4];
            #pragma unroll
            for (int mt = 0; mt < 4; mt++) {
                #pragma unroll
                for (int j = 0; j < 8; j++) {
                    float d = fmaf(-alv[j], sig, dus[mt]);
                    float e = __expf(-(d * d));       // <= 1, no overflow
                    lsum[mt] += e;
                    afrag[mt][j] = f2bf(e);
                }
            }
            #pragma unroll
            for (int nt = 0; nt < 8; nt++) {
                short8 bfrag = *(const short8*)&bT[nt * 16 + lm][ks * 32 + quad * 8];
                #pragma unroll
                for (int mt = 0; mt < 4; mt++)
                    acc[mt][nt] = __builtin_amdgcn_mfma_f32_16x16x32_bf16(
                        afrag[mt], bfrag, acc[mt][nt], 0, 0, 0);
            }
        }
    }

    // l partial: reduce across quads (same u lives in lanes lm, lm+16, lm+32, lm+48)
    #pragma unroll
    for (int mt = 0; mt < 4; mt++) {
        float v = lsum[mt];
        v += __shfl_xor(v, 16, 64);
        v += __shfl_xor(v, 32, 64);
        if (quad == 0)
            atomicAdd(&l_ws[(((b * kH) + h) << 8) + u_base + mt * 16 + lm], v);
    }

    // O partial: D layout col=lane&15, row=quad*4+reg (m89/m91-verified)
    #pragma unroll
    for (int mt = 0; mt < 4; mt++) {
        #pragma unroll
        for (int r = 0; r < 4; r++) {
            int u = u_base + mt * 16 + quad * 4 + r;
            if (u < kU) {
                float* dst = out_ac + ((size_t)(b * kU + u)) * kC + h * kDH + lm;
                #pragma unroll
                for (int nt = 0; nt < 8; nt++)
                    atomicAdd(dst + nt * 16, acc[mt][nt][r]);
            }
        }
    }
}

// ---------------- K4: normalize O by per-(b,h,u) l ----------------
__global__ __launch_bounds__(256) void k4_norm(
    float* __restrict__ out_ac, const float* __restrict__ l_ws)
{
    const int idx = blockIdx.x * 256 + threadIdx.x;      // float4 index
    const int e = idx * 4;
    if (e >= kB * kU * kC) return;
    const int b = e / (kU * kC);
    const int rem = e - b * (kU * kC);
    const int u = rem / kC;
    const int c = rem - u * kC;
    const int h = c >> 7;
    float l = l_ws[(((b * kH) + h) << 8) + u];
    float linv = (l > 0.f) ? 1.f / l : 0.f;
    float4 v = *(float4*)&out_ac[e];
    v.x *= linv; v.y *= linv; v.z *= linv; v.w *= linv;
    *(float4*)&out_ac[e] = v;
}

extern "C" void kernel_launch(void* const* d_in, const int* in_sizes, int n_in,
                              void* d_out, int out_size, void* d_ws, size_t ws_size,
                              hipStream_t stream) {
    const float* hid    = (const float*)d_in[0];
    const float* mask   = (const float*)d_in[1];
    const int*   tgt    = (const int*)d_in[2];
    // d_in[3] = max_token scalar (compile-time kU=250)
    const float* conv_w = (const float*)d_in[4];
    const float* conv_b = (const float*)d_in[5];
    const float* lin_w  = (const float*)d_in[6];
    const float* lin_b  = (const float*)d_in[7];
    const float* sigma  = (const float*)d_in[8];
    // d_in[9] = sigma_bias: constant over t -> cancels in softmax; unused.

    float* alpha_raw = (float*)d_ws;                        // [B*T]
    float* align_m   = alpha_raw + (size_t)kB * kT;         // [B*T]
    float* l_ws      = align_m + (size_t)kB * kT;           // [B*H*256]

    float* out_ac    = (float*)d_out;                       // [B, U, C]
    float* out_tok   = out_ac + (size_t)kB * kU * kC;       // [B]
    float* out_alpha = out_tok + kB;                        // [B, T]

    hipMemsetAsync(out_ac, 0, (size_t)kB * kU * kC * sizeof(float), stream);
    hipMemsetAsync(l_ws, 0, (size_t)kB * kH * 256 * sizeof(float), stream);

    k1_alpha<<<kB * kT / 4, 256, 0, stream>>>(hid, mask, conv_w, conv_b, lin_w, lin_b, alpha_raw);
    k2_scan<<<kB, 256, 0, stream>>>(alpha_raw, mask, tgt, align_m, out_tok, out_alpha);
    k3_attn<<<dim3(kTC, kH, kB), 256, 0, stream>>>(hid, align_m, sigma, out_ac, l_ws);
    const int n4 = (kB * kU * kC) / 4;
    k4_norm<<<(n4 + 255) / 256, 256, 0, stream>>>(out_ac, l_ws);
}

// Round 6
// 175.160 us; speedup vs baseline: 2.3747x; 1.1769x over previous
//
#include <hip/hip_runtime.h>
#include <hip/hip_bf16.h>

namespace {
constexpr int kB = 16, kT = 2048, kC = 512, kH = 4, kU = 250, kDH = 128;
constexpr int kDS = 4;          // d-split blocks per (b,h)
constexpr int kDW = 32;         // d per block
constexpr int kTT = 256;        // t-tile staged per iteration
constexpr int kNST = kT / kTT;  // 8
constexpr int kPitch = 264;     // bT row pitch in shorts (16B-aligned rows)
}

typedef __attribute__((ext_vector_type(8))) short short8;
typedef __attribute__((ext_vector_type(4))) float float4v;

__device__ __forceinline__ short f2bf(float x) {
    union { float f; unsigned int u; } v; v.f = x;
    unsigned int r = (v.u + 0x7FFFu + ((v.u >> 16) & 1u)) >> 16;
    return (short)r;
}

// ---------------- K1: alpha prediction branch ----------------
// wave = 8 consecutive t of one b; 10 hidden rows kept in registers (1.25x read amp).
__global__ __launch_bounds__(256) void k1_alpha(
    const float* __restrict__ hid, const float* __restrict__ mask,
    const float* __restrict__ conv_w, const float* __restrict__ conv_b,
    const float* __restrict__ lin_w, const float* __restrict__ lin_b,
    float* __restrict__ alpha_raw)
{
    const int wave = threadIdx.x >> 6, lane = threadIdx.x & 63;
    const int gw = blockIdx.x * 4 + wave;
    const int b = gw >> 8;                 // 256 waves per b
    const int t0 = (gw & 255) << 3;
    const int c0 = lane * 8;

    float cw[24], cb[8], lw[8];
    #pragma unroll
    for (int i = 0; i < 6; i++) *(float4*)&cw[i*4] = ((const float4*)(conv_w + c0*3))[i];
    *(float4*)&cb[0] = *(const float4*)(conv_b + c0);
    *(float4*)&cb[4] = *(const float4*)(conv_b + c0 + 4);
    *(float4*)&lw[0] = *(const float4*)(lin_w + c0);
    *(float4*)&lw[4] = *(const float4*)(lin_w + c0 + 4);
    const float lb = lin_b[0];

    float r[10][8];
    const float* base = hid + ((size_t)b * kT + t0) * kC + c0;
    #pragma unroll
    for (int i = 0; i < 10; i++) {
        const int tt = t0 + i - 1;
        if (tt >= 0 && tt < kT) {
            const float* p = base + (ptrdiff_t)(i - 1) * kC;
            *(float4*)&r[i][0] = *(const float4*)p;
            *(float4*)&r[i][4] = *(const float4*)(p + 4);
        } else {
            #pragma unroll
            for (int j = 0; j < 8; j++) r[i][j] = 0.f;
        }
    }

    float sums[8];
    #pragma unroll
    for (int j = 0; j < 8; j++) {
        float acc = 0.f;
        #pragma unroll
        for (int k = 0; k < 8; k++) {
            float m = fmaf(r[j][k], cw[k*3],
                      fmaf(r[j+1][k], cw[k*3+1],
                      fmaf(r[j+2][k], cw[k*3+2], cb[k])));
            float v = m + r[j+1][k];          // memory + context
            v = v > 0.f ? v : 0.f;            // relu
            acc = fmaf(v, lw[k], acc);
        }
        #pragma unroll
        for (int off = 32; off >= 1; off >>= 1) acc += __shfl_xor(acc, off, 64);
        sums[j] = acc;
    }
    if (lane == 0) {
        #pragma unroll
        for (int j = 0; j < 8; j++) {
            float s = sums[j] + lb;
            float a = 1.f / (1.f + expf(-s));  // relu(sigmoid*1-0) == sigmoid
            alpha_raw[(size_t)b * kT + t0 + j] = a * mask[(size_t)b * kT + t0 + j];
        }
    }
}

// ---------------- K2: token_num, scaling, cumsum (parallel scan) ----------------
__global__ __launch_bounds__(256) void k2_scan(
    const float* __restrict__ alpha_raw, const float* __restrict__ mask,
    const int* __restrict__ target,
    float* __restrict__ align_out,
    float* __restrict__ out_tok, float* __restrict__ out_alpha)
{
    __shared__ float wtot[4];
    __shared__ float s_tot;
    const int b = blockIdx.x;
    const int tid = threadIdx.x;
    const int wave = tid >> 6, lane = tid & 63;

    const float* ar = alpha_raw + (size_t)b * kT + tid * 8;
    float raw[8], pre[8];
    float s = 0.f;
    #pragma unroll
    for (int j = 0; j < 8; j++) { raw[j] = ar[j]; s += raw[j]; pre[j] = s; }

    // wave inclusive scan of per-thread sums
    float sc = s;
    #pragma unroll
    for (int off = 1; off <= 32; off <<= 1) {
        float v = __shfl_up(sc, off, 64);
        sc = (lane >= off) ? sc + v : sc;
    }
    if (lane == 63) wtot[wave] = sc;
    __syncthreads();
    if (tid == 0) {
        float a0 = wtot[0], a1 = wtot[1], a2 = wtot[2], a3 = wtot[3];
        wtot[0] = 0.f; wtot[1] = a0; wtot[2] = a0 + a1; wtot[3] = a0 + a1 + a2;
        s_tot = a0 + a1 + a2 + a3;
    }
    __syncthreads();
    const float run = s_tot;
    const float scale = (run != 0.f) ? ((float)target[b] / run) : 0.f;
    const float basev = wtot[wave] + (sc - s);   // exclusive prefix for this thread
    if (tid == 0) out_tok[b] = run;

    const float* mp = mask + (size_t)b * kT + tid * 8;
    float* al = align_out + (size_t)b * kT + tid * 8;
    float* oa = out_alpha + (size_t)b * kT + tid * 8;
    #pragma unroll
    for (int j = 0; j < 8; j++) {
        float cum = (basev + pre[j]) * scale;
        al[j] = (mp[j] > 0.f) ? cum : 1.0e30f;   // mask fold: far value => weight 0
        oa[j] = raw[j] * scale;
    }
}

// ---------------- K3: MFMA Gaussian soft-segment attention, d-split ----------------
// grid (ds=4, h=4, b=16) = 256 blocks; block owns d-slice [ds*32, ds*32+32) of head h,
// loops full T => disjoint output, no atomics. Wave = 64 u (4 mt) x 32 d (2 nt).
// Per-u softmax max computed exactly via binary search on monotone alignment.
__global__ __launch_bounds__(256) void k3_attn(
    const float* __restrict__ hid, const float* __restrict__ align_m,
    const float* __restrict__ sigma, float* __restrict__ out_ac)
{
    __shared__ float al_s[kT];                    // 8 KB
    __shared__ unsigned short bT[kDW * kPitch];   // 16.9 KB, [d][t] bf16

    const int ds = blockIdx.x, h = blockIdx.y, b = blockIdx.z;
    const int tid = threadIdx.x;
    const int wave = tid >> 6, lane = tid & 63;
    const int lm = lane & 15, quad = lane >> 4;
    const float sig = sigma[h];

    {
        const float4* src = (const float4*)(align_m + (size_t)b * kT);
        float4* dst = (float4*)al_s;
        dst[tid] = src[tid];
        dst[tid + 256] = src[tid + 256];
    }
    __syncthreads();

    // per-lane/mt: du*sig, exact softmax max via binary search (al_s monotone)
    const int u_base = wave * 64;
    float dus[4], mu_pos[4];
    float dmax_l = 0.f;
    #pragma unroll
    for (int mt = 0; mt < 4; mt++) {
        const float du = (float)(u_base + mt * 16 + lm) + 0.5f;
        dus[mt] = du * sig;
        int pos = 0;
        #pragma unroll
        for (int stp = 1024; stp >= 1; stp >>= 1) {
            int np = pos + stp;
            pos = (al_s[np - 1] < du) ? np : pos;
        }
        float d1 = (pos < kT) ? al_s[pos] - du : 3.0e30f;
        float d0 = (pos > 0) ? du - al_s[pos - 1] : 3.0e30f;
        float dmin = fminf(d0, d1);
        float ms = fminf(dmin, 1.0e4f) * sig;
        mu_pos[mt] = ms * ms;                       // = -max_score (>=0)
        dmax_l = fmaxf(dmax_l, fminf(dmin, 300.f));
    }
    // wave max of dmin (for conservative window test)
    #pragma unroll
    for (int off = 32; off >= 1; off >>= 1) dmax_l = fmaxf(dmax_l, __shfl_xor(dmax_l, off, 64));
    const float W = (sig > 1e-6f) ? 9.4f / sig : 1.0e30f;   // exp(-88) cutoff width
    const float skip_thr = dmax_l + W;
    const float u_lo = (float)u_base + 0.5f;
    const float u_hi = (float)u_base + 63.5f;

    float4v acc[4][2];
    #pragma unroll
    for (int mt = 0; mt < 4; mt++) { acc[mt][0] = (float4v)(0.f); acc[mt][1] = (float4v)(0.f); }
    float lsum[4] = {0.f, 0.f, 0.f, 0.f};

    // staging mapping: thread -> 2 t-rows x 16 d
    const int tl = (tid & 127) * 2;
    const int dbase = (tid >> 7) * 16;
    const float* hrow = hid + (size_t)b * kT * kC + h * kDH + ds * kDW + dbase;

    float4 a0[4], a1[4];
    {
        const float* p0 = hrow + (size_t)tl * kC;
        #pragma unroll
        for (int i = 0; i < 4; i++) { a0[i] = ((const float4*)p0)[i]; a1[i] = ((const float4*)(p0 + kC))[i]; }
    }

    for (int st = 0; st < kNST; st++) {
        __syncthreads();                 // previous tile's readers done
        #pragma unroll
        for (int i = 0; i < 4; i++) {
            const float* p0 = (const float*)&a0[i];
            const float* p1 = (const float*)&a1[i];
            #pragma unroll
            for (int e = 0; e < 4; e++) {
                unsigned int lo = (unsigned int)(unsigned short)f2bf(p0[e]);
                unsigned int hi = (unsigned int)(unsigned short)f2bf(p1[e]);
                *(unsigned int*)&bT[(dbase + i * 4 + e) * kPitch + tl] = lo | (hi << 16);
            }
        }
        __syncthreads();
        if (st + 1 < kNST) {             // prefetch next tile (overlaps compute)
            const float* p0 = hrow + (size_t)((st + 1) * kTT + tl) * kC;
            #pragma unroll
            for (int i = 0; i < 4; i++) { a0[i] = ((const float4*)p0)[i]; a1[i] = ((const float4*)(p0 + kC))[i]; }
        }

        #pragma unroll
        for (int ks = 0; ks < 8; ks++) {
            const int kb = st * kTT + ks * 32;
            // wave-uniform window test: can this 32-t chunk contribute > exp(-88)?
            float al_lo = al_s[kb], al_hi = al_s[kb + 31];
            float g = fmaxf(fmaxf(u_lo - al_hi, al_lo - u_hi), 0.f);
            if (g > skip_thr) continue;

            float alv[8];
            *(float4*)&alv[0] = *(const float4*)&al_s[kb + quad * 8];
            *(float4*)&alv[4] = *(const float4*)&al_s[kb + quad * 8 + 4];

            short8 afrag[4];
            #pragma unroll
            for (int mt = 0; mt < 4; mt++) {
                #pragma unroll
                for (int j = 0; j < 8; j++) {
                    float d = fmaf(-alv[j], sig, dus[mt]);        // (du-al)*sig
                    float e = __expf(fmaf(-d, d, -mu_pos[mt]) * -1.0f * -1.0f + 0.0f);
                    e = __expf(fmaf(-d, d, mu_pos[mt]) * 1.0f);   // exp(mu_pos - d^2) <= 1
                    lsum[mt] += e;
                    afrag[mt][j] = f2bf(e);
                }
            }
            short8 bf0 = *(const short8*)&bT[(0 * 16 + lm) * kPitch + ks * 32 + quad * 8];
            short8 bf1 = *(const short8*)&bT[(1 * 16 + lm) * kPitch + ks * 32 + quad * 8];
            #pragma unroll
            for (int mt = 0; mt < 4; mt++) {
                acc[mt][0] = __builtin_amdgcn_mfma_f32_16x16x32_bf16(afrag[mt], bf0, acc[mt][0], 0, 0, 0);
                acc[mt][1] = __builtin_amdgcn_mfma_f32_16x16x32_bf16(afrag[mt], bf1, acc[mt][1], 0, 0, 0);
            }
        }
    }

    // epilogue: reduce l across quads, normalize, direct store (disjoint => no atomics)
    #pragma unroll
    for (int mt = 0; mt < 4; mt++) {
        float lv = lsum[mt];
        lv += __shfl_xor(lv, 16, 64);
        lv += __shfl_xor(lv, 32, 64);    // all lanes: l for u = u_base + mt*16 + lm
        #pragma unroll
        for (int r = 0; r < 4; r++) {
            int ur = quad * 4 + r;
            float rl = __shfl(lv, ur, 64);            // l for u = u_base + mt*16 + ur
            float linv = (rl > 1e-30f) ? 1.f / rl : 0.f;
            int u = u_base + mt * 16 + ur;
            if (u < kU) {
                float* dst = out_ac + ((size_t)(b * kU + u)) * kC + h * kDH + ds * kDW + lm;
                dst[0]  = acc[mt][0][r] * linv;
                dst[16] = acc[mt][1][r] * linv;
            }
        }
    }
}

extern "C" void kernel_launch(void* const* d_in, const int* in_sizes, int n_in,
                              void* d_out, int out_size, void* d_ws, size_t ws_size,
                              hipStream_t stream) {
    const float* hid    = (const float*)d_in[0];
    const float* mask   = (const float*)d_in[1];
    const int*   tgt    = (const int*)d_in[2];
    // d_in[3] = max_token scalar (compile-time kU=250)
    const float* conv_w = (const float*)d_in[4];
    const float* conv_b = (const float*)d_in[5];
    const float* lin_w  = (const float*)d_in[6];
    const float* lin_b  = (const float*)d_in[7];
    const float* sigma  = (const float*)d_in[8];
    // d_in[9] = sigma_bias: constant over t -> cancels in softmax; unused.

    float* alpha_raw = (float*)d_ws;                     // [B*T]
    float* align_m   = alpha_raw + (size_t)kB * kT;      // [B*T]

    float* out_ac    = (float*)d_out;                    // [B, U, C]
    float* out_tok   = out_ac + (size_t)kB * kU * kC;    // [B]
    float* out_alpha = out_tok + kB;                     // [B, T]

    k1_alpha<<<kB * kT / 32, 256, 0, stream>>>(hid, mask, conv_w, conv_b, lin_w, lin_b, alpha_raw);
    k2_scan<<<kB, 256, 0, stream>>>(alpha_raw, mask, tgt, align_m, out_tok, out_alpha);
    k3_attn<<<dim3(kDS, kH, kB), 256, 0, stream>>>(hid, align_m, sigma, out_ac);
}

// Round 7
// 138.008 us; speedup vs baseline: 3.0140x; 1.2692x over previous
//
#include <hip/hip_runtime.h>
#include <hip/hip_bf16.h>

namespace {
constexpr int kB = 16, kT = 2048, kC = 512, kH = 4, kU = 250, kDH = 128;
constexpr int kDS = 4;          // d-split blocks per (b,h)
constexpr int kDW = 32;         // d per block
constexpr int kTT = 256;        // t-tile staged per iteration
constexpr int kNST = kT / kTT;  // 8
constexpr int kPitch = 264;     // bT row pitch in shorts (16B-aligned rows, pitch%64!=0)
}

typedef __attribute__((ext_vector_type(8))) short short8;
typedef __attribute__((ext_vector_type(4))) float float4v;

__device__ __forceinline__ short f2bf(float x) {
    union { float f; unsigned int u; } v; v.f = x;
    unsigned int r = (v.u + 0x7FFFu + ((v.u >> 16) & 1u)) >> 16;
    return (short)r;
}

// ---------------- K1: alpha prediction branch ----------------
// wave = 8 consecutive t of one b; 10 hidden rows kept in registers (1.25x read amp).
__global__ __launch_bounds__(256) void k1_alpha(
    const float* __restrict__ hid, const float* __restrict__ mask,
    const float* __restrict__ conv_w, const float* __restrict__ conv_b,
    const float* __restrict__ lin_w, const float* __restrict__ lin_b,
    float* __restrict__ alpha_raw)
{
    const int wave = threadIdx.x >> 6, lane = threadIdx.x & 63;
    const int gw = blockIdx.x * 4 + wave;
    const int b = gw >> 8;                 // 256 waves per b
    const int t0 = (gw & 255) << 3;
    const int c0 = lane * 8;

    float cw[24], cb[8], lw[8];
    #pragma unroll
    for (int i = 0; i < 6; i++) *(float4*)&cw[i*4] = ((const float4*)(conv_w + c0*3))[i];
    *(float4*)&cb[0] = *(const float4*)(conv_b + c0);
    *(float4*)&cb[4] = *(const float4*)(conv_b + c0 + 4);
    *(float4*)&lw[0] = *(const float4*)(lin_w + c0);
    *(float4*)&lw[4] = *(const float4*)(lin_w + c0 + 4);
    const float lb = lin_b[0];

    float r[10][8];
    const float* base = hid + ((size_t)b * kT + t0) * kC + c0;
    #pragma unroll
    for (int i = 0; i < 10; i++) {
        const int tt = t0 + i - 1;
        if (tt >= 0 && tt < kT) {
            const float* p = base + (ptrdiff_t)(i - 1) * kC;
            *(float4*)&r[i][0] = *(const float4*)p;
            *(float4*)&r[i][4] = *(const float4*)(p + 4);
        } else {
            #pragma unroll
            for (int j = 0; j < 8; j++) r[i][j] = 0.f;
        }
    }

    float sums[8];
    #pragma unroll
    for (int j = 0; j < 8; j++) {
        float acc = 0.f;
        #pragma unroll
        for (int k = 0; k < 8; k++) {
            float m = fmaf(r[j][k], cw[k*3],
                      fmaf(r[j+1][k], cw[k*3+1],
                      fmaf(r[j+2][k], cw[k*3+2], cb[k])));
            float v = m + r[j+1][k];          // memory + context
            v = v > 0.f ? v : 0.f;            // relu
            acc = fmaf(v, lw[k], acc);
        }
        #pragma unroll
        for (int off = 32; off >= 1; off >>= 1) acc += __shfl_xor(acc, off, 64);
        sums[j] = acc;
    }
    if (lane == 0) {
        #pragma unroll
        for (int j = 0; j < 8; j++) {
            float s = sums[j] + lb;
            float a = 1.f / (1.f + expf(-s));  // relu(sigmoid*1-0) == sigmoid
            alpha_raw[(size_t)b * kT + t0 + j] = a * mask[(size_t)b * kT + t0 + j];
        }
    }
}

// ---------------- K2: token_num, scaling, cumsum (parallel scan) ----------------
__global__ __launch_bounds__(256) void k2_scan(
    const float* __restrict__ alpha_raw, const float* __restrict__ mask,
    const int* __restrict__ target,
    float* __restrict__ align_out,
    float* __restrict__ out_tok, float* __restrict__ out_alpha)
{
    __shared__ float wtot[4];
    __shared__ float s_tot;
    const int b = blockIdx.x;
    const int tid = threadIdx.x;
    const int wave = tid >> 6, lane = tid & 63;

    const float* ar = alpha_raw + (size_t)b * kT + tid * 8;
    float raw[8], pre[8];
    float s = 0.f;
    #pragma unroll
    for (int j = 0; j < 8; j++) { raw[j] = ar[j]; s += raw[j]; pre[j] = s; }

    // wave inclusive scan of per-thread sums
    float sc = s;
    #pragma unroll
    for (int off = 1; off <= 32; off <<= 1) {
        float v = __shfl_up(sc, off, 64);
        sc = (lane >= off) ? sc + v : sc;
    }
    if (lane == 63) wtot[wave] = sc;
    __syncthreads();
    if (tid == 0) {
        float a0 = wtot[0], a1 = wtot[1], a2 = wtot[2], a3 = wtot[3];
        wtot[0] = 0.f; wtot[1] = a0; wtot[2] = a0 + a1; wtot[3] = a0 + a1 + a2;
        s_tot = a0 + a1 + a2 + a3;
    }
    __syncthreads();
    const float run = s_tot;
    const float scale = (run != 0.f) ? ((float)target[b] / run) : 0.f;
    const float basev = wtot[wave] + (sc - s);   // exclusive prefix for this thread
    if (tid == 0) out_tok[b] = run;

    const float* mp = mask + (size_t)b * kT + tid * 8;
    float* al = align_out + (size_t)b * kT + tid * 8;
    float* oa = out_alpha + (size_t)b * kT + tid * 8;
    #pragma unroll
    for (int j = 0; j < 8; j++) {
        float cum = (basev + pre[j]) * scale;
        al[j] = (mp[j] > 0.f) ? cum : 1.0e30f;   // mask fold: far value => weight 0
        oa[j] = raw[j] * scale;
    }
}

// ---------------- K3: MFMA Gaussian soft-segment attention, d-split ----------------
// grid (ds=4, h=4, b=16) = 256 blocks x 1024 thr (16 waves => 4 waves/SIMD).
// Block owns d-slice [ds*32, +32) of head h, loops full T => disjoint output, no atomics.
// Wave = 16 u (1 m-tile) x 32 d (2 n-tiles). Per-u softmax max exact via binary
// search on monotone alignment; per-wave contributing t-range precomputed once
// (banded weights) so most chunks are skipped wave-uniformly.
__global__ __launch_bounds__(1024) void k3_attn(
    const float* __restrict__ hid, const float* __restrict__ align_m,
    const float* __restrict__ sigma, float* __restrict__ out_ac)
{
    __shared__ float al_s[kT];                    // 8 KB
    __shared__ unsigned short bT[kDW * kPitch];   // 16.9 KB, [d][t] bf16

    const int ds = blockIdx.x, h = blockIdx.y, b = blockIdx.z;
    const int tid = threadIdx.x;
    const int wave = tid >> 6, lane = tid & 63;
    const int lm = lane & 15, quad = lane >> 4;
    const float sig = sigma[h];

    if (tid < 512)
        ((float4*)al_s)[tid] = ((const float4*)(align_m + (size_t)b * kT))[tid];
    __syncthreads();

    // per-lane u; exact softmax max via binary search (al_s monotone)
    const int u_base = wave * 16;
    const float du = (float)(u_base + lm) + 0.5f;
    const float dusig = du * sig;
    int pos = 0;
    #pragma unroll
    for (int stp = 1024; stp >= 1; stp >>= 1) {
        int np = pos + stp;
        pos = (al_s[np - 1] < du) ? np : pos;
    }
    float d1 = (pos < kT) ? al_s[pos] - du : 3.0e30f;
    float d0 = (pos > 0) ? du - al_s[pos - 1] : 3.0e30f;
    float dmin = fminf(fminf(d0, d1), 300.f);     // 300 > max possible true dmin (255.5)
    float ms = dmin * sig;
    const float mu_pos = ms * ms;                 // = -max_score (>= 0)

    // wave-uniform contributing t-range: |du - al| <= dmin_max + 9.4/sig
    float dmax_l = dmin;
    #pragma unroll
    for (int off = 32; off >= 1; off >>= 1) dmax_l = fmaxf(dmax_l, __shfl_xor(dmax_l, off, 64));
    const float W = (sig > 1e-6f) ? 9.4f / sig : 3.0e30f;
    const float lo_b = (float)u_base + 0.5f - dmax_l - W;
    const float hi_b = (float)u_base + 15.5f + dmax_l + W;
    int p_lo = 0, p_hi = 0;
    #pragma unroll
    for (int stp = 1024; stp >= 1; stp >>= 1) {
        int n1 = p_lo + stp; p_lo = (al_s[n1 - 1] < lo_b) ? n1 : p_lo;
        int n2 = p_hi + stp; p_hi = (al_s[n2 - 1] < hi_b) ? n2 : p_hi;
    }
    const int ks_lo = p_lo >> 5;            // first contributing 32-chunk
    const int ks_end = (p_hi + 31) >> 5;    // exclusive

    float4v acc0 = (float4v)(0.f), acc1 = (float4v)(0.f);
    float lsum = 0.f;

    // staging mapping: thread -> 2 t-rows x 4 d
    const int tl = (tid & 127) * 2;
    const int dbase = (tid >> 7) * 4;
    const float* hrow = hid + (size_t)b * kT * kC + h * kDH + ds * kDW + dbase;

    float4 a0, a1;
    a0 = *(const float4*)(hrow + (size_t)tl * kC);
    a1 = *(const float4*)(hrow + (size_t)(tl + 1) * kC);

    for (int st = 0; st < kNST; st++) {
        __syncthreads();                 // previous tile's readers done
        {
            const float* p0 = (const float*)&a0;
            const float* p1 = (const float*)&a1;
            #pragma unroll
            for (int e = 0; e < 4; e++) {
                unsigned int lo = (unsigned int)(unsigned short)f2bf(p0[e]);
                unsigned int hi = (unsigned int)(unsigned short)f2bf(p1[e]);
                *(unsigned int*)&bT[(dbase + e) * kPitch + tl] = lo | (hi << 16);
            }
        }
        __syncthreads();
        if (st + 1 < kNST) {             // prefetch next tile (overlaps compute)
            const float* p0 = hrow + (size_t)((st + 1) * kTT + tl) * kC;
            a0 = *(const float4*)p0;
            a1 = *(const float4*)(p0 + kC);
        }

        #pragma unroll
        for (int ks = 0; ks < 8; ks++) {
            const int kg = st * 8 + ks;
            if (kg < ks_lo || kg >= ks_end) continue;   // wave-uniform band skip
            const int kb = kg * 32;

            float alv[8];
            *(float4*)&alv[0] = *(const float4*)&al_s[kb + quad * 8];
            *(float4*)&alv[4] = *(const float4*)&al_s[kb + quad * 8 + 4];

            short8 afrag;
            #pragma unroll
            for (int j = 0; j < 8; j++) {
                float d = fmaf(-alv[j], sig, dusig);      // (du - al) * sig
                float e = __expf(fmaf(-d, d, mu_pos));    // exp(max - d^2) <= 1
                lsum += e;
                afrag[j] = f2bf(e);
            }
            short8 bf0 = *(const short8*)&bT[lm * kPitch + ks * 32 + quad * 8];
            short8 bf1 = *(const short8*)&bT[(16 + lm) * kPitch + ks * 32 + quad * 8];
            acc0 = __builtin_amdgcn_mfma_f32_16x16x32_bf16(afrag, bf0, acc0, 0, 0, 0);
            acc1 = __builtin_amdgcn_mfma_f32_16x16x32_bf16(afrag, bf1, acc1, 0, 0, 0);
        }
    }

    // epilogue: reduce l across quads, normalize, direct store (disjoint => no atomics)
    float lv = lsum;
    lv += __shfl_xor(lv, 16, 64);
    lv += __shfl_xor(lv, 32, 64);        // every lane: full l for u = u_base + lm
    #pragma unroll
    for (int r = 0; r < 4; r++) {
        const int ur = quad * 4 + r;
        float rl = __shfl(lv, ur, 64);   // l for u = u_base + ur
        float linv = (rl > 1e-30f) ? 1.f / rl : 0.f;
        const int u = u_base + ur;
        if (u < kU) {
            float* dst = out_ac + ((size_t)(b * kU + u)) * kC + h * kDH + ds * kDW + lm;
            dst[0]  = acc0[r] * linv;
            dst[16] = acc1[r] * linv;
        }
    }
}

extern "C" void kernel_launch(void* const* d_in, const int* in_sizes, int n_in,
                              void* d_out, int out_size, void* d_ws, size_t ws_size,
                              hipStream_t stream) {
    const float* hid    = (const float*)d_in[0];
    const float* mask   = (const float*)d_in[1];
    const int*   tgt    = (const int*)d_in[2];
    // d_in[3] = max_token scalar (compile-time kU=250)
    const float* conv_w = (const float*)d_in[4];
    const float* conv_b = (const float*)d_in[5];
    const float* lin_w  = (const float*)d_in[6];
    const float* lin_b  = (const float*)d_in[7];
    const float* sigma  = (const float*)d_in[8];
    // d_in[9] = sigma_bias: constant over t -> cancels in softmax; unused.

    float* alpha_raw = (float*)d_ws;                     // [B*T]
    float* align_m   = alpha_raw + (size_t)kB * kT;      // [B*T]

    float* out_ac    = (float*)d_out;                    // [B, U, C]
    float* out_tok   = out_ac + (size_t)kB * kU * kC;    // [B]
    float* out_alpha = out_tok + kB;                     // [B, T]

    k1_alpha<<<kB * kT / 32, 256, 0, stream>>>(hid, mask, conv_w, conv_b, lin_w, lin_b, alpha_raw);
    k2_scan<<<kB, 256, 0, stream>>>(alpha_raw, mask, tgt, align_m, out_tok, out_alpha);
    k3_attn<<<dim3(kDS, kH, kB), 1024, 0, stream>>>(hid, align_m, sigma, out_ac);
}